// Round 7
// baseline (106.242 us; speedup 1.0000x reference)
//
#include <hip/hip_runtime.h>

typedef _Float16 f16;
typedef _Float16 f16x8 __attribute__((ext_vector_type(8)));
typedef float f32x4 __attribute__((ext_vector_type(4)));

#define BD 512  // D == H == 512

// async global->LDS, 16B per lane. LDS dest = wave-uniform base (+ lane*16 by HW).
__device__ __forceinline__ void llds16(const f16* g, f16* l) {
  __builtin_amdgcn_global_load_lds(
      (const __attribute__((address_space(1))) unsigned int*)g,
      (__attribute__((address_space(3))) unsigned int*)l,
      16, 0, 0);
}

// ---- prep: W fp32->f16 (1,048,576 elems) + zero novelty accumulators ----
__global__ __launch_bounds__(256) void prep_kernel(
    const float* __restrict__ projW, const float* __restrict__ opsW,
    f16* __restrict__ wh, float* __restrict__ novAcc,
    unsigned int* __restrict__ novCnt) {
  if (blockIdx.x == 0 && threadIdx.x == 0) { *novAcc = 0.f; *novCnt = 0u; }
  const int e = (blockIdx.x * 256 + threadIdx.x) * 8;
  const float* s = (e < 262144) ? (projW + e) : (opsW + (e - 262144));
  float4 v0 = ((const float4*)s)[0];
  float4 v1 = ((const float4*)s)[1];
  f16x8 h;
  h[0]=(f16)v0.x; h[1]=(f16)v0.y; h[2]=(f16)v0.z; h[3]=(f16)v0.w;
  h[4]=(f16)v1.x; h[5]=(f16)v1.y; h[6]=(f16)v1.z; h[7]=(f16)v1.w;
  *(f16x8*)&wh[e] = h;
}

// ---- mega2: 256 blocks x 512 thr; block = 32 rows x all 512 cols, 3 layers in LDS ----
// W fed via global_load_lds ring (BK=32, 2 slices), ONE continuous 48-step pipeline.
__global__ __launch_bounds__(512, 1) void mega2_kernel(
    const float* __restrict__ x, const float* __restrict__ memf,
    const float* __restrict__ logits, const f16* __restrict__ wh,
    const float* __restrict__ projB, const float* __restrict__ opsB,
    float* __restrict__ out, float* __restrict__ novAcc,
    unsigned int* __restrict__ novCnt) {
  __shared__ __align__(16) f16 act0[32 * BD];      // 32 KB (chunk-swizzled)
  __shared__ __align__(16) f16 act1[32 * BD];      // 32 KB
  __shared__ __align__(16) f16 wring[2][16384];    // 2 x 32 KB W slices (linear)
  __shared__ float xn[32];

  const int t = threadIdx.x, l = t & 63, w = t >> 6;
  const int bid = blockIdx.x;
  const int lr = l & 15, lk = l >> 4;

  // ---- routing: top-2 of 3 logits (softmax monotonic; ties -> lower idx) ----
  const float l0 = logits[0], l1 = logits[1], l2 = logits[2];
  int ia = 0; float ba = l0;
  if (l1 > ba) { ba = l1; ia = 1; }
  if (l2 > ba) { ba = l2; ia = 2; }
  int ib = 0; float bb2 = -3.4e38f;
  if (ia != 0)             { bb2 = l0; ib = 0; }
  if (ia != 1 && l1 > bb2) { bb2 = l1; ib = 1; }
  if (ia != 2 && l2 > bb2) { bb2 = l2; ib = 2; }

  // ---- phase A: x fp32 -> f16 into swizzled LDS panel + row sumsq ----
  {
    const int r  = t >> 4;          // 0..31 block-local row
    const int cg = t & 15;          // 16 col-groups of 32 f32
    const float* src = x + ((size_t)bid * 32 + r) * BD + cg * 32;
    float ss = 0.f;
    #pragma unroll
    for (int j = 0; j < 4; ++j) {
      float4 v0 = ((const float4*)src)[2 * j];
      float4 v1 = ((const float4*)src)[2 * j + 1];
      f16x8 h;
      h[0]=(f16)v0.x; h[1]=(f16)v0.y; h[2]=(f16)v0.z; h[3]=(f16)v0.w;
      h[4]=(f16)v1.x; h[5]=(f16)v1.y; h[6]=(f16)v1.z; h[7]=(f16)v1.w;
      const int ch = cg * 4 + j;    // 16B chunk 0..63
      *(f16x8*)&act0[r * BD + ((ch ^ (r & 7)) << 3)] = h;
      ss += v0.x*v0.x + v0.y*v0.y + v0.z*v0.z + v0.w*v0.w
          + v1.x*v1.x + v1.y*v1.y + v1.z*v1.z + v1.w*v1.w;
    }
    ss += __shfl_xor(ss, 1, 16); ss += __shfl_xor(ss, 2, 16);
    ss += __shfl_xor(ss, 4, 16); ss += __shfl_xor(ss, 8, 16);
    if (cg == 0) xn[r] = ss;
  }
  __syncthreads();

  // ---- novelty: all 8 waves; wave = (x-half w>>2) x (mem-group w&3) ----
  {
    const int mg = w & 3, xh2 = w >> 2;
    const int mm = mg * 16 + lr;
    f32x4 nacc = (f32x4){0.f,0.f,0.f,0.f};
    float msq = 0.f;
    #pragma unroll 4
    for (int kk = 0; kk < BD; kk += 32) {
      f16x8 bfr;
      if (mm < 50) {
        const float* ms = memf + (size_t)mm * BD + kk + lk * 8;
        float4 v0 = ((const float4*)ms)[0];
        float4 v1 = ((const float4*)ms)[1];
        bfr[0]=(f16)v0.x; bfr[1]=(f16)v0.y; bfr[2]=(f16)v0.z; bfr[3]=(f16)v0.w;
        bfr[4]=(f16)v1.x; bfr[5]=(f16)v1.y; bfr[6]=(f16)v1.z; bfr[7]=(f16)v1.w;
        msq += v0.x*v0.x + v0.y*v0.y + v0.z*v0.z + v0.w*v0.w
             + v1.x*v1.x + v1.y*v1.y + v1.z*v1.z + v1.w*v1.w;
      } else {
        #pragma unroll
        for (int j = 0; j < 8; ++j) bfr[j] = (f16)0.f;
      }
      const int ch = (kk >> 3) + lk;
      f16x8 afr = *(const f16x8*)&act0[(xh2 * 16 + lr) * BD + ((ch ^ (lr & 7)) << 3)];
      nacc = __builtin_amdgcn_mfma_f32_16x16x32_f16(afr, bfr, nacc, 0, 0, 0);
    }
    msq += __shfl_xor(msq, 16, 64);
    msq += __shfl_xor(msq, 32, 64);
    float local = 0.f;
    if (mm < 50) {
      #pragma unroll
      for (int j = 0; j < 4; ++j) {
        const int row = xh2 * 16 + lk * 4 + j;   // C/D: row=(lane>>4)*4+j
        float d = xn[row] - 2.f * nacc[j] + msq;
        local += sqrtf(fmaxf(d, 0.f));
      }
    }
    #pragma unroll
    for (int off = 32; off; off >>= 1) local += __shfl_down(local, off, 64);
    if (l == 0) {
      atomicAdd(novAcc, local);
      __threadfence();
      const unsigned old = atomicAdd(novCnt, 1u);
      if (old == 2047u) {             // last of 256 blocks x 8 waves
        __threadfence();
        const float tot = atomicAdd(novAcc, 0.f);
        out[4194304] = fminf(1.5f, tot * (1.0f / (8192.0f * 50.0f)));
      }
    }
  }

  // ---- preload all 12 bias values so the K-loop has ONLY counted llds16 VMEM ----
  const f16* W0 = wh;
  const f16* W1 = wh + 262144 + (size_t)ia * 262144;
  const f16* W2 = wh + 262144 + (size_t)ib * 262144;
  float bias_[3][4];
  #pragma unroll
  for (int n = 0; n < 4; ++n) {
    const int colg = w * 64 + n * 16 + lr;
    bias_[0][n] = projB[colg];
    bias_[1][n] = opsB[ia * BD + colg];
    bias_[2][n] = opsB[ib * BD + colg];
  }
  asm volatile("s_waitcnt vmcnt(0)" ::: "memory");
  __syncthreads();   // act0 final + all prior VMEM drained; vmcnt baseline = 0

  // stage W slice s (s = L*16 + tt): 32 KB, 4 llds16/thread, linear layout
  auto stageS = [&](int s) {
    const f16* Wl = (s < 16) ? W0 : (s < 32) ? W1 : W2;
    const int kt = (s & 15) * 32;
    f16* dst = &wring[s & 1][0];
    #pragma unroll
    for (int i = 0; i < 4; ++i) {
      const int o = i * 8192 + t * 16;   // byte offset in 32 KB slice
      const int row = o >> 6;            // 64 B per row (32 f16)
      const int c = (o >> 4) & 3;
      llds16(Wl + (size_t)row * BD + kt + c * 8, dst + (i * 8192 + w * 1024) / 2);
    }
  };

  stageS(0);
  stageS(1);

  #pragma unroll
  for (int L = 0; L < 3; ++L) {
    const f16* actIn = (L == 1) ? act1 : act0;
    f32x4 acc[2][4];
    #pragma unroll
    for (int m = 0; m < 2; ++m)
      #pragma unroll
      for (int n = 0; n < 4; ++n) acc[m][n] = (f32x4){0.f,0.f,0.f,0.f};

    #pragma unroll
    for (int tt = 0; tt < 16; ++tt) {
      const int s = L * 16 + tt;
      if (s == 47) asm volatile("s_waitcnt vmcnt(0)" ::: "memory");
      else         asm volatile("s_waitcnt vmcnt(4)" ::: "memory");
      __builtin_amdgcn_s_barrier();      // slice s fully in LDS (all waves)

      const f16* Wb = &wring[s & 1][0];
      const int ch = tt * 4 + lk;
      f16x8 af0 = *(const f16x8*)&actIn[lr * BD + ((ch ^ (lr & 7)) << 3)];
      f16x8 af1 = *(const f16x8*)&actIn[(16 + lr) * BD + ((ch ^ (lr & 7)) << 3)];
      f16x8 bf[4];
      #pragma unroll
      for (int n = 0; n < 4; ++n)
        bf[n] = *(const f16x8*)&Wb[(w * 64 + n * 16 + lr) * 32 + lk * 8];

      __builtin_amdgcn_s_setprio(1);
      #pragma unroll
      for (int n = 0; n < 4; ++n) {
        acc[0][n] = __builtin_amdgcn_mfma_f32_16x16x32_f16(af0, bf[n], acc[0][n], 0, 0, 0);
        acc[1][n] = __builtin_amdgcn_mfma_f32_16x16x32_f16(af1, bf[n], acc[1][n], 0, 0, 0);
      }
      __builtin_amdgcn_s_setprio(0);

      asm volatile("s_waitcnt lgkmcnt(0)" ::: "memory");  // ds_reads of slice s done
      __builtin_amdgcn_s_barrier();      // safe to overwrite buf (s&1) next
      if (s + 2 < 48) stageS(s + 2);
    }

    // epilogue: bias + relu
    if (L < 2) {
      f16* actOut = (L == 0) ? act1 : act0;
      #pragma unroll
      for (int n = 0; n < 4; ++n) {
        const int colg = w * 64 + n * 16 + lr;
        #pragma unroll
        for (int m = 0; m < 2; ++m) {
          #pragma unroll
          for (int j = 0; j < 4; ++j) {
            const int row = m * 16 + lk * 4 + j;
            const float v = fmaxf(acc[m][n][j] + bias_[L][n], 0.f);
            const int ch2 = colg >> 3;
            actOut[row * BD + ((ch2 ^ (row & 7)) << 3) + (colg & 7)] = (f16)v;
          }
        }
      }
      asm volatile("s_waitcnt lgkmcnt(0)" ::: "memory");
      __builtin_amdgcn_s_barrier();      // actOut complete for next layer
    } else {
      #pragma unroll
      for (int n = 0; n < 4; ++n) {
        const int colg = w * 64 + n * 16 + lr;
        #pragma unroll
        for (int m = 0; m < 2; ++m) {
          #pragma unroll
          for (int j = 0; j < 4; ++j) {
            const int row = m * 16 + lk * 4 + j;
            const float v = fmaxf(acc[m][n][j] + bias_[2][n], 0.f);
            out[((size_t)bid * 32 + row) * BD + colg] = v;
          }
        }
      }
    }
  }
}

extern "C" void kernel_launch(void* const* d_in, const int* in_sizes, int n_in,
                              void* d_out, int out_size, void* d_ws, size_t ws_size,
                              hipStream_t stream) {
  const float* x      = (const float*)d_in[0];   // [8192,512]
  const float* memf   = (const float*)d_in[1];   // [50,512]
  const float* logits = (const float*)d_in[2];   // [3]
  const float* projW  = (const float*)d_in[3];   // [512,512]
  const float* projB  = (const float*)d_in[4];   // [512]
  const float* opsW   = (const float*)d_in[5];   // [3,512,512]
  const float* opsB   = (const float*)d_in[6];   // [3,512]
  float* out = (float*)d_out;                    // [8192*512 + 1]

  char* ws = (char*)d_ws;
  f16*   wh     = (f16*)(ws);                 // 2 MB: proj_W f16, then ops_W f16
  float* novAcc = (float*)(ws + 2097152);     // 4 B
  unsigned int* novCnt = (unsigned int*)(ws + 2097156);  // 4 B

  prep_kernel<<<512, 256, 0, stream>>>(projW, opsW, wh, novAcc, novCnt);
  mega2_kernel<<<256, 512, 0, stream>>>(x, memf, logits, wh, projB, opsB,
                                        out, novAcc, novCnt);
}

// Round 8
// 51.393 us; speedup vs baseline: 2.0672x; 2.0672x over previous
//
#include <hip/hip_runtime.h>
#include <hip/hip_bf16.h>

typedef _Float16 f16;
typedef _Float16 f16x8 __attribute__((ext_vector_type(8)));
typedef float f32x4 __attribute__((ext_vector_type(4)));

#define BD 512  // D == H == 512

// async global->LDS, 16B per lane. LDS dest is wave-uniform base + lane*16.
__device__ __forceinline__ void llds16(const f16* g, f16* l) {
  __builtin_amdgcn_global_load_lds(
      (const __attribute__((address_space(1))) unsigned int*)g,
      (__attribute__((address_space(3))) unsigned int*)l,
      16, 0, 0);
}

// ---- fused: weight cvt + x cvt + row norms + novelty partials (256 blocks) ----
__global__ __launch_bounds__(256) void conv_nov_w_kernel(
    const float* __restrict__ x, const float* __restrict__ memf,
    const float* __restrict__ projW, const float* __restrict__ opsW,
    f16* __restrict__ wh, f16* __restrict__ xh,
    float* __restrict__ novPart) {
  __shared__ __align__(16) f16 As[32 * BD];   // 32 KB, chunk-swizzled
  __shared__ float xn[32];
  __shared__ float red[4];
  const int t = threadIdx.x, l = t & 63, w = t >> 6;
  const int rbase = blockIdx.x * 32;

  // weights: 1,048,576 f16 total = 256 blocks * 256 thr * 16 each (16 | 262144)
  {
    const int e = (blockIdx.x * 256 + t) * 16;
    const float* s = (e < 262144) ? (projW + e) : (opsW + (e - 262144));
    float4 v0 = ((const float4*)s)[0];
    float4 v1 = ((const float4*)s)[1];
    float4 v2 = ((const float4*)s)[2];
    float4 v3 = ((const float4*)s)[3];
    f16x8 h0, h1;
    h0[0]=(f16)v0.x; h0[1]=(f16)v0.y; h0[2]=(f16)v0.z; h0[3]=(f16)v0.w;
    h0[4]=(f16)v1.x; h0[5]=(f16)v1.y; h0[6]=(f16)v1.z; h0[7]=(f16)v1.w;
    h1[0]=(f16)v2.x; h1[1]=(f16)v2.y; h1[2]=(f16)v2.z; h1[3]=(f16)v2.w;
    h1[4]=(f16)v3.x; h1[5]=(f16)v3.y; h1[6]=(f16)v3.z; h1[7]=(f16)v3.w;
    *(f16x8*)&wh[e] = h0;
    *(f16x8*)&wh[e + 8] = h1;
  }

  // phase 1: convert rows w*8..w*8+7; lane l covers cols l*8..l*8+7
  #pragma unroll
  for (int rr = 0; rr < 8; ++rr) {
    const int r = w * 8 + rr;
    const float* src = x + (size_t)(rbase + r) * BD + l * 8;
    float4 v0 = *(const float4*)src;
    float4 v1 = *(const float4*)(src + 4);
    f16x8 h;
    h[0]=(f16)v0.x; h[1]=(f16)v0.y; h[2]=(f16)v0.z; h[3]=(f16)v0.w;
    h[4]=(f16)v1.x; h[5]=(f16)v1.y; h[6]=(f16)v1.z; h[7]=(f16)v1.w;
    *(f16x8*)&xh[(size_t)(rbase + r) * BD + l * 8] = h;
    const int cs = l ^ (r & 7);               // chunk swizzle (low 3 bits)
    *(f16x8*)&As[r * BD + cs * 8] = h;
    float ss = v0.x*v0.x + v0.y*v0.y + v0.z*v0.z + v0.w*v0.w
             + v1.x*v1.x + v1.y*v1.y + v1.z*v1.z + v1.w*v1.w;
    #pragma unroll
    for (int off = 32; off; off >>= 1) ss += __shfl_down(ss, off, 64);
    if (l == 0) xn[r] = ss;
  }
  __syncthreads();

  // phase 2: wave w handles mem rows w*16..+15 (f16 in regs), x rows 0..31.
  // K-order skewed by block id so concurrent blocks hit different mem lines.
  const int lr = l & 15, lk = l >> 4;
  const int mm = w * 16 + lr;
  const int skw = blockIdx.x & 15;
  f32x4 acc0 = (f32x4){0.f, 0.f, 0.f, 0.f};
  f32x4 acc1 = (f32x4){0.f, 0.f, 0.f, 0.f};
  float msq = 0.f;
  #pragma unroll
  for (int kk8 = 0; kk8 < 16; ++kk8) {
    const int kk = ((kk8 + skw) & 15) * 32;
    f16x8 bfr;
    if (mm < 50) {
      const float* ms = memf + (size_t)mm * BD + kk + lk * 8;
      float4 v0 = ((const float4*)ms)[0];
      float4 v1 = ((const float4*)ms)[1];
      bfr[0]=(f16)v0.x; bfr[1]=(f16)v0.y; bfr[2]=(f16)v0.z; bfr[3]=(f16)v0.w;
      bfr[4]=(f16)v1.x; bfr[5]=(f16)v1.y; bfr[6]=(f16)v1.z; bfr[7]=(f16)v1.w;
      msq += v0.x*v0.x + v0.y*v0.y + v0.z*v0.z + v0.w*v0.w
           + v1.x*v1.x + v1.y*v1.y + v1.z*v1.z + v1.w*v1.w;
    } else {
      #pragma unroll
      for (int j = 0; j < 8; ++j) bfr[j] = (f16)0.f;
    }
    const int ch = (kk >> 3) + lk;
    {
      const int row0 = lr;
      f16x8 a0 = *(const f16x8*)&As[row0 * BD + ((ch ^ (row0 & 7)) << 3)];
      acc0 = __builtin_amdgcn_mfma_f32_16x16x32_f16(a0, bfr, acc0, 0, 0, 0);
      const int row1 = 16 + lr;
      f16x8 a1 = *(const f16x8*)&As[row1 * BD + ((ch ^ (row1 & 7)) << 3)];
      acc1 = __builtin_amdgcn_mfma_f32_16x16x32_f16(a1, bfr, acc1, 0, 0, 0);
    }
  }
  float local = 0.f;
  if (mm < 50) {
    #pragma unroll
    for (int j = 0; j < 4; ++j) {
      const int r0 = lk * 4 + j;             // C/D: row = (lane>>4)*4 + j
      float d0 = xn[r0] - 2.f * acc0[j] + msq;
      local += sqrtf(fmaxf(d0, 0.f));
      float d1 = xn[16 + r0] - 2.f * acc1[j] + msq;
      local += sqrtf(fmaxf(d1, 0.f));
    }
  }
  #pragma unroll
  for (int off = 32; off; off >>= 1) local += __shfl_down(local, off, 64);
  if (l == 0) red[w] = local;
  __syncthreads();
  if (t == 0) novPart[blockIdx.x] = red[0] + red[1] + red[2] + red[3];
}

// ---- GEMM: out = relu(A @ W^T + bias), 64x128 tile, BK=64, 3-buffer ring ----
// XCD-swizzled block mapping + per-block K-rotation to kill same-line L2 contention.
// PICK: 0 = proj (also finalizes novelty); 1 = ops_W[idx_a]; 2 = ops_W[idx_b]
template <int PICK, int OUTF16>
__global__ __launch_bounds__(256, 2) void gemm_relu_kernel(
    const f16* __restrict__ A, const f16* __restrict__ Wall,
    const float* __restrict__ ball, const float* __restrict__ logits,
    void* __restrict__ Out, const float* __restrict__ novPart,
    float* __restrict__ novOut) {
  __shared__ __align__(16) char lds[3 * 24576];  // per buf: 8 KB A + 16 KB B

  const int t = threadIdx.x;
  const int l = t & 63;
  const int w = t >> 6;
  const int wr = w >> 1, wc = w & 1;          // wave tile: rows wr*32, cols wc*64
  const int lr = l & 15, lk = l >> 4;

  if (PICK == 0 && blockIdx.x == 0 && blockIdx.y == 0 && w == 0) {
    float s = novPart[l] + novPart[l + 64] + novPart[l + 128] + novPart[l + 192];
    #pragma unroll
    for (int off = 32; off; off >>= 1) s += __shfl_down(s, off, 64);
    if (l == 0) novOut[0] = fminf(1.5f, s * (1.0f / (8192.0f * 50.0f)));
  }

  int widx = 0;
  if (PICK > 0) {
    float l0 = logits[0], l1 = logits[1], l2 = logits[2];
    int ia = 0; float ba = l0;
    if (l1 > ba) { ba = l1; ia = 1; }
    if (l2 > ba) { ba = l2; ia = 2; }
    if (PICK == 1) {
      widx = ia;
    } else {
      int ib = 0; float bb2 = -3.4e38f;
      if (ia != 0)             { bb2 = l0; ib = 0; }
      if (ia != 1 && l1 > bb2) { bb2 = l1; ib = 1; }
      if (ia != 2 && l2 > bb2) { bb2 = l2; ib = 2; }
      widx = ib;
    }
  }
  const f16* W = Wall + (size_t)widx * BD * BD;
  const float* bias = ball + widx * BD;

  // XCD-aware remap: linear id -> (bx in 0..127, by in 0..3) with by = xcd>>1,
  // so each XCD's CUs share one B-panel (L2-local).
  const int id = blockIdx.y * 128 + blockIdx.x;   // HW dispatch order (x-major)
  const int xcd = id & 7;
  const int q = id >> 3;                          // 0..63
  const int bx = (q << 1) | (xcd & 1);            // 0..127
  const int by = xcd >> 1;                        // 0..3
  const int skw = bx & 7;                         // per-block K rotation

  const int rowBase = bx * 64;
  const int colBase = by * 128;

  f32x4 acc[2][4];
  #pragma unroll
  for (int m = 0; m < 2; ++m)
    #pragma unroll
    for (int n = 0; n < 4; ++n) acc[m][n] = (f32x4){0.f, 0.f, 0.f, 0.f};

  // stage one K-tile into ring buffer buf: A 8 KB (2 loads/thr), B 16 KB (4 loads/thr)
  auto stage = [&](int buf, int kt) {
    f16* Ab = (f16*)(lds + buf * 24576);
    f16* Bb = (f16*)(lds + buf * 24576 + 8192);
    #pragma unroll
    for (int i = 0; i < 2; ++i) {
      const int o = i * 4096 + t * 16;       // byte offset in 8 KB A tile
      const int row = o >> 7;                // 128 B per row (64 f16)
      const int sch = ((o >> 4) & 7) ^ (row & 7);
      llds16(A + (size_t)(rowBase + row) * BD + kt + sch * 8,
             Ab + (i * 4096 + w * 1024) / 2);
    }
    #pragma unroll
    for (int i = 0; i < 4; ++i) {
      const int o = i * 4096 + t * 16;       // byte offset in 16 KB B tile
      const int row = o >> 7;
      const int sch = ((o >> 4) & 7) ^ (row & 7);
      llds16(W + (size_t)(colBase + row) * BD + kt + sch * 8,
             Bb + (i * 4096 + w * 1024) / 2);
    }
  };

  auto compute = [&](int buf) {
    const f16* Ab = (const f16*)(lds + buf * 24576);
    const f16* Bb = (const f16*)(lds + buf * 24576 + 8192);
    #pragma unroll
    for (int kk = 0; kk < 64; kk += 32) {
      f16x8 af[2], bf[4];
      #pragma unroll
      for (int m = 0; m < 2; ++m) {
        const int row = wr * 32 + m * 16 + lr;
        const int ch = (kk >> 3) + lk;
        af[m] = *(const f16x8*)&Ab[row * 64 + ((ch ^ (row & 7)) << 3)];
      }
      #pragma unroll
      for (int n = 0; n < 4; ++n) {
        const int row = wc * 64 + n * 16 + lr;
        const int ch = (kk >> 3) + lk;
        bf[n] = *(const f16x8*)&Bb[row * 64 + ((ch ^ (row & 7)) << 3)];
      }
      __builtin_amdgcn_s_setprio(1);
      #pragma unroll
      for (int m = 0; m < 2; ++m)
        #pragma unroll
        for (int n = 0; n < 4; ++n)
          acc[m][n] = __builtin_amdgcn_mfma_f32_16x16x32_f16(af[m], bf[n], acc[m][n], 0, 0, 0);
      __builtin_amdgcn_s_setprio(0);
    }
  };

  // 3-deep ring, ONE barrier per K-step, counted vmcnt (never 0 mid-loop).
  // K-tile order rotated by skw: kt(i) = ((i+skw)&7)*64.
  stage(0, ((0 + skw) & 7) * 64);
  stage(1, ((1 + skw) & 7) * 64);
  #pragma unroll
  for (int t8 = 0; t8 < 8; ++t8) {
    if (t8 < 7) asm volatile("s_waitcnt vmcnt(6)" ::: "memory");
    else        asm volatile("s_waitcnt vmcnt(0)" ::: "memory");
    __builtin_amdgcn_s_barrier();            // tile t8 fully in LDS (all waves)
    if (t8 < 6) stage((t8 + 2) % 3, ((t8 + 2 + skw) & 7) * 64);
    compute(t8 % 3);
    asm volatile("s_waitcnt lgkmcnt(0)" ::: "memory");  // ds_reads drained
  }

  // epilogue: bias + relu, store
  #pragma unroll
  for (int n = 0; n < 4; ++n) {
    const int col = colBase + wc * 64 + n * 16 + lr;
    const float bbv = bias[col];
    #pragma unroll
    for (int m = 0; m < 2; ++m) {
      #pragma unroll
      for (int j = 0; j < 4; ++j) {
        const int rowg = rowBase + wr * 32 + m * 16 + lk * 4 + j;
        float v = fmaxf(acc[m][n][j] + bbv, 0.f);
        if (OUTF16) ((f16*)Out)[(size_t)rowg * BD + col] = (f16)v;
        else        ((float*)Out)[(size_t)rowg * BD + col] = v;
      }
    }
  }
}

extern "C" void kernel_launch(void* const* d_in, const int* in_sizes, int n_in,
                              void* d_out, int out_size, void* d_ws, size_t ws_size,
                              hipStream_t stream) {
  const float* x      = (const float*)d_in[0];   // [8192,512]
  const float* memf   = (const float*)d_in[1];   // [50,512]
  const float* logits = (const float*)d_in[2];   // [3]
  const float* projW  = (const float*)d_in[3];   // [512,512]
  const float* projB  = (const float*)d_in[4];   // [512]
  const float* opsW   = (const float*)d_in[5];   // [3,512,512]
  const float* opsB   = (const float*)d_in[6];   // [3,512]
  float* out = (float*)d_out;                    // [8192*512 + 1]

  char* ws = (char*)d_ws;
  f16*   xh      = (f16*)(ws);               // 8 MB (x f16; reused as h1)
  f16*   g0      = (f16*)(ws + 8388608);     // 8 MB
  f16*   wh      = (f16*)(ws + 16777216);    // 2 MB: proj_W f16, then ops_W f16
  float* novPart = (float*)(ws + 18874368);  // 1 KB (256 floats)

  conv_nov_w_kernel<<<256, 256, 0, stream>>>(x, memf, projW, opsW, wh, xh, novPart);

  // g0 = relu(xh @ projW^T + projB); also finalizes novelty scalar
  gemm_relu_kernel<0, 1><<<dim3(128, 4), 256, 0, stream>>>(
      xh, wh, projB, logits, (void*)g0, novPart, out + 4194304);
  // h1 = relu(g0 @ Wa^T + ba)   (overwrites xh)
  gemm_relu_kernel<1, 1><<<dim3(128, 4), 256, 0, stream>>>(
      g0, wh + 262144, opsB, logits, (void*)xh, novPart, out + 4194304);
  // out = relu(h1 @ Wb^T + bb)  (fp32 out)
  gemm_relu_kernel<2, 0><<<dim3(128, 4), 256, 0, stream>>>(
      xh, wh + 262144, opsB, logits, (void*)out, novPart, out + 4194304);
}

// Round 10
// 47.018 us; speedup vs baseline: 2.2596x; 1.0931x over previous
//
#include <hip/hip_runtime.h>
#include <hip/hip_bf16.h>

typedef _Float16 f16;
typedef _Float16 f16x8 __attribute__((ext_vector_type(8)));
typedef float f32x4 __attribute__((ext_vector_type(4)));

#define BD 512  // D == H == 512

// async global->LDS, 16B per lane. LDS dest is wave-uniform base + lane*16.
__device__ __forceinline__ void llds16(const f16* g, f16* l) {
  __builtin_amdgcn_global_load_lds(
      (const __attribute__((address_space(1))) unsigned int*)g,
      (__attribute__((address_space(3))) unsigned int*)l,
      16, 0, 0);
}

// ---- fused: weight cvt + x cvt + row norms + novelty partials (512 blocks, 16 rows) ----
__global__ __launch_bounds__(256) void conv_nov_w_kernel(
    const float* __restrict__ x, const float* __restrict__ memf,
    const float* __restrict__ projW, const float* __restrict__ opsW,
    f16* __restrict__ wh, f16* __restrict__ xh,
    float* __restrict__ novPart) {
  __shared__ __align__(16) f16 As[16 * BD];   // 16 KB, chunk-swizzled
  __shared__ float xn[16];
  __shared__ float red[4];
  const int t = threadIdx.x, l = t & 63, w = t >> 6;
  const int rbase = blockIdx.x * 16;

  // weights: 1,048,576 f16 total = 512 blocks * 256 thr * 8 each
  {
    const int e = (blockIdx.x * 256 + t) * 8;
    const float* s = (e < 262144) ? (projW + e) : (opsW + (e - 262144));
    float4 v0 = ((const float4*)s)[0];
    float4 v1 = ((const float4*)s)[1];
    f16x8 h;
    h[0]=(f16)v0.x; h[1]=(f16)v0.y; h[2]=(f16)v0.z; h[3]=(f16)v0.w;
    h[4]=(f16)v1.x; h[5]=(f16)v1.y; h[6]=(f16)v1.z; h[7]=(f16)v1.w;
    *(f16x8*)&wh[e] = h;
  }

  // phase 1: convert rows w*4..w*4+3 (4 waves x 4 rows = 16); lane l covers cols l*8..l*8+7
  #pragma unroll
  for (int rr = 0; rr < 4; ++rr) {
    const int r = w * 4 + rr;
    const float* src = x + (size_t)(rbase + r) * BD + l * 8;
    float4 v0 = *(const float4*)src;
    float4 v1 = *(const float4*)(src + 4);
    f16x8 h;
    h[0]=(f16)v0.x; h[1]=(f16)v0.y; h[2]=(f16)v0.z; h[3]=(f16)v0.w;
    h[4]=(f16)v1.x; h[5]=(f16)v1.y; h[6]=(f16)v1.z; h[7]=(f16)v1.w;
    *(f16x8*)&xh[(size_t)(rbase + r) * BD + l * 8] = h;
    const int cs = l ^ (r & 7);               // chunk swizzle (low 3 bits)
    *(f16x8*)&As[r * BD + cs * 8] = h;
    float ss = v0.x*v0.x + v0.y*v0.y + v0.z*v0.z + v0.w*v0.w
             + v1.x*v1.x + v1.y*v1.y + v1.z*v1.z + v1.w*v1.w;
    #pragma unroll
    for (int off = 32; off; off >>= 1) ss += __shfl_down(ss, off, 64);
    if (l == 0) xn[r] = ss;
  }
  __syncthreads();

  // phase 2: waves 0..3 handle mem rows w*16..+15 (f16 in regs), x rows 0..15
  const int lr = l & 15, lk = l >> 4;
  if (w < 4) {
    const int mm = w * 16 + lr;
    f32x4 acc = (f32x4){0.f, 0.f, 0.f, 0.f};
    float msq = 0.f;
    #pragma unroll
    for (int kk = 0; kk < BD; kk += 32) {
      f16x8 bfr;
      if (mm < 50) {
        const float* ms = memf + (size_t)mm * BD + kk + lk * 8;
        float4 v0 = ((const float4*)ms)[0];
        float4 v1 = ((const float4*)ms)[1];
        bfr[0]=(f16)v0.x; bfr[1]=(f16)v0.y; bfr[2]=(f16)v0.z; bfr[3]=(f16)v0.w;
        bfr[4]=(f16)v1.x; bfr[5]=(f16)v1.y; bfr[6]=(f16)v1.z; bfr[7]=(f16)v1.w;
        msq += v0.x*v0.x + v0.y*v0.y + v0.z*v0.z + v0.w*v0.w
             + v1.x*v1.x + v1.y*v1.y + v1.z*v1.z + v1.w*v1.w;
      } else {
        #pragma unroll
        for (int j = 0; j < 8; ++j) bfr[j] = (f16)0.f;
      }
      const int ch = (kk >> 3) + lk;
      f16x8 a = *(const f16x8*)&As[lr * BD + ((ch ^ (lr & 7)) << 3)];
      acc = __builtin_amdgcn_mfma_f32_16x16x32_f16(a, bfr, acc, 0, 0, 0);
    }
    msq += __shfl_xor(msq, 16, 64);
    msq += __shfl_xor(msq, 32, 64);
    float local = 0.f;
    if (mm < 50) {
      #pragma unroll
      for (int j = 0; j < 4; ++j) {
        const int r0 = lk * 4 + j;             // C/D: row = (lane>>4)*4 + j
        float d = xn[r0] - 2.f * acc[j] + msq;
        local += sqrtf(fmaxf(d, 0.f));
      }
    }
    #pragma unroll
    for (int off = 32; off; off >>= 1) local += __shfl_down(local, off, 64);
    if (l == 0) red[w] = local;
  }
  __syncthreads();
  if (t == 0) novPart[blockIdx.x] = red[0] + red[1] + red[2] + red[3];
}

// ---- GEMM: out = relu(A @ W^T + bias), 64x64 tile, 4 waves of 32x32, BK=64, ring-3 ----
// grid (128,8) = 1024 blocks; 48 KB LDS -> 3 blocks/CU = 12 waves/CU.
// PICK: 0 = proj (also finalizes novelty); 1 = ops_W[idx_a]; 2 = ops_W[idx_b]
template <int PICK, int OUTF16>
__global__ __launch_bounds__(256, 3) void gemm_relu_kernel(
    const f16* __restrict__ A, const f16* __restrict__ Wall,
    const float* __restrict__ ball, const float* __restrict__ logits,
    void* __restrict__ Out, const float* __restrict__ novPart,
    float* __restrict__ novOut) {
  __shared__ __align__(16) char lds[3 * 16384];  // per buf: 8 KB A + 8 KB B

  const int t = threadIdx.x;
  const int l = t & 63;
  const int w = t >> 6;
  const int wr = w >> 1, wc = w & 1;          // wave tile: rows wr*32, cols wc*32
  const int lr = l & 15, lk = l >> 4;

  if (PICK == 0 && blockIdx.x == 0 && blockIdx.y == 0 && w == 0) {
    float s = 0.f;
    #pragma unroll
    for (int i = 0; i < 8; ++i) s += novPart[l + i * 64];
    #pragma unroll
    for (int off = 32; off; off >>= 1) s += __shfl_down(s, off, 64);
    if (l == 0) novOut[0] = fminf(1.5f, s * (1.0f / (8192.0f * 50.0f)));
  }

  int widx = 0;
  if (PICK > 0) {
    float l0 = logits[0], l1 = logits[1], l2 = logits[2];
    int ia = 0; float ba = l0;
    if (l1 > ba) { ba = l1; ia = 1; }
    if (l2 > ba) { ba = l2; ia = 2; }
    if (PICK == 1) {
      widx = ia;
    } else {
      int ib = 0; float bb2 = -3.4e38f;
      if (ia != 0)             { bb2 = l0; ib = 0; }
      if (ia != 1 && l1 > bb2) { bb2 = l1; ib = 1; }
      if (ia != 2 && l2 > bb2) { bb2 = l2; ib = 2; }
      widx = ib;
    }
  }
  const f16* W = Wall + (size_t)widx * BD * BD;
  const float* bias = ball + widx * BD;

  const int rowBase = blockIdx.x * 64;
  const int colBase = blockIdx.y * 64;

  f32x4 acc[2][2];
  #pragma unroll
  for (int m = 0; m < 2; ++m)
    #pragma unroll
    for (int n = 0; n < 2; ++n) acc[m][n] = (f32x4){0.f, 0.f, 0.f, 0.f};

  // stage one K-tile (64x64 A + 64x64 B, 8 KB each): 4 llds16/thread
  auto stage = [&](int buf, int kt) {
    f16* Ab = (f16*)(lds + buf * 16384);
    f16* Bb = (f16*)(lds + buf * 16384 + 8192);
    #pragma unroll
    for (int i = 0; i < 2; ++i) {
      const int o = i * 4096 + t * 16;       // byte offset in 8 KB tile
      const int row = o >> 7;                // 128 B per row (64 f16)
      const int sch = ((o >> 4) & 7) ^ (row & 7);
      llds16(A + (size_t)(rowBase + row) * BD + kt + sch * 8,
             Ab + (i * 4096 + w * 1024) / 2);
      llds16(W + (size_t)(colBase + row) * BD + kt + sch * 8,
             Bb + (i * 4096 + w * 1024) / 2);
    }
  };

  auto compute = [&](int buf) {
    const f16* Ab = (const f16*)(lds + buf * 16384);
    const f16* Bb = (const f16*)(lds + buf * 16384 + 8192);
    #pragma unroll
    for (int kk = 0; kk < 64; kk += 32) {
      const int ch = (kk >> 3) + lk;
      f16x8 af[2], bf[2];
      #pragma unroll
      for (int m = 0; m < 2; ++m) {
        const int row = wr * 32 + m * 16 + lr;
        af[m] = *(const f16x8*)&Ab[row * 64 + ((ch ^ (row & 7)) << 3)];
      }
      #pragma unroll
      for (int n = 0; n < 2; ++n) {
        const int row = wc * 32 + n * 16 + lr;
        bf[n] = *(const f16x8*)&Bb[row * 64 + ((ch ^ (row & 7)) << 3)];
      }
      __builtin_amdgcn_s_setprio(1);
      #pragma unroll
      for (int m = 0; m < 2; ++m)
        #pragma unroll
        for (int n = 0; n < 2; ++n)
          acc[m][n] = __builtin_amdgcn_mfma_f32_16x16x32_f16(af[m], bf[n], acc[m][n], 0, 0, 0);
      __builtin_amdgcn_s_setprio(0);
    }
  };

  // 3-deep ring, ONE barrier per K-step, counted vmcnt (never 0 mid-loop).
  stage(0, 0);
  stage(1, 64);
  #pragma unroll
  for (int t8 = 0; t8 < 8; ++t8) {
    if (t8 < 7) asm volatile("s_waitcnt vmcnt(4)" ::: "memory");
    else        asm volatile("s_waitcnt vmcnt(0)" ::: "memory");
    __builtin_amdgcn_s_barrier();            // tile t8 fully in LDS (all waves)
    if (t8 < 6) stage((t8 + 2) % 3, (t8 + 2) * 64);
    compute(t8 % 3);
    asm volatile("s_waitcnt lgkmcnt(0)" ::: "memory");  // my ds_reads drained
  }

  // epilogue: bias + relu, store
  #pragma unroll
  for (int n = 0; n < 2; ++n) {
    const int col = colBase + wc * 32 + n * 16 + lr;
    const float bbv = bias[col];
    #pragma unroll
    for (int m = 0; m < 2; ++m) {
      #pragma unroll
      for (int j = 0; j < 4; ++j) {
        const int rowg = rowBase + wr * 32 + m * 16 + lk * 4 + j;
        float v = fmaxf(acc[m][n][j] + bbv, 0.f);
        if (OUTF16) ((f16*)Out)[(size_t)rowg * BD + col] = (f16)v;
        else        ((float*)Out)[(size_t)rowg * BD + col] = v;
      }
    }
  }
}

extern "C" void kernel_launch(void* const* d_in, const int* in_sizes, int n_in,
                              void* d_out, int out_size, void* d_ws, size_t ws_size,
                              hipStream_t stream) {
  const float* x      = (const float*)d_in[0];   // [8192,512]
  const float* memf   = (const float*)d_in[1];   // [50,512]
  const float* logits = (const float*)d_in[2];   // [3]
  const float* projW  = (const float*)d_in[3];   // [512,512]
  const float* projB  = (const float*)d_in[4];   // [512]
  const float* opsW   = (const float*)d_in[5];   // [3,512,512]
  const float* opsB   = (const float*)d_in[6];   // [3,512]
  float* out = (float*)d_out;                    // [8192*512 + 1]

  char* ws = (char*)d_ws;
  f16*   xh      = (f16*)(ws);               // 8 MB (x f16; reused as h1)
  f16*   g0      = (f16*)(ws + 8388608);     // 8 MB
  f16*   wh      = (f16*)(ws + 16777216);    // 2 MB: proj_W f16, then ops_W f16
  float* novPart = (float*)(ws + 18874368);  // 2 KB (512 floats)

  conv_nov_w_kernel<<<512, 256, 0, stream>>>(x, memf, projW, opsW, wh, xh, novPart);

  // g0 = relu(xh @ projW^T + projB); also finalizes novelty scalar
  gemm_relu_kernel<0, 1><<<dim3(128, 8), 256, 0, stream>>>(
      xh, wh, projB, logits, (void*)g0, novPart, out + 4194304);
  // h1 = relu(g0 @ Wa^T + ba)   (overwrites xh)
  gemm_relu_kernel<1, 1><<<dim3(128, 8), 256, 0, stream>>>(
      g0, wh + 262144, opsB, logits, (void*)xh, novPart, out + 4194304);
  // out = relu(h1 @ Wb^T + bb)  (fp32 out)
  gemm_relu_kernel<2, 0><<<dim3(128, 8), 256, 0, stream>>>(
      xh, wh + 262144, opsB, logits, (void*)out, novPart, out + 4194304);
}